// Round 18
// baseline (119.608 us; speedup 1.0000x reference)
//
#include <hip/hip_runtime.h>
#include <math.h>

// CRF forward loss — ROUND 18 PROBE: identical R17 kernels, but crf_fold is
// launched 3x (idempotent: identical rewrites; `done` finale fires only in
// fold #1). T = 75.8 + 2*fold_time isolates fold vs fixed overhead.

constexpr int S_LEN   = 512;
constexpr int NB      = 32;
constexpr int NL      = 64;
constexpr int LL      = 4096;
constexpr int CL      = 16;
constexpr int NCH     = 32;            // chunks per batch
constexpr int NCHUNKS = NB * NCH;      // 1024
constexpr int XSTR    = 68;            // padded exchange stride (f16)

#define LN2F 0.69314718055994531f
#define PREF 4.6588830833596715f       /* ln(64)+0.5 : M = exp(E)*e^-PREF */

typedef _Float16 h4 __attribute__((ext_vector_type(4)));
typedef float    f4 __attribute__((ext_vector_type(4)));
union U4 { unsigned u[2]; h4 v; };

__device__ __forceinline__ float bl(float v, int sl) {
  return __int_as_float(__builtin_amdgcn_readlane(__float_as_int(v), sl));
}
__device__ __forceinline__ unsigned pk2(float a, float b) {
  auto r = __builtin_amdgcn_cvt_pkrtz(a, b);
  return __builtin_bit_cast(unsigned, r);
}
__device__ __forceinline__ float expw(float x) {   // exp(x)*e^-PREF, native
  return __expf(x - PREF);
}

// ---------------- Phase 1: chunk products (2-wave split chain) --------------
__global__ __launch_bounds__(128, 2) void crf_chunk(
    const float* __restrict__ emits,
    const int*   __restrict__ targets,
    const int*   __restrict__ mask,
    _Float16*    __restrict__ matP,   // [1024][4096] f16
    float*       __restrict__ wsf)    // [0,1024): Lacc ; [1024,2048): gold
{
  __shared__ _Float16 xch[64 * XSTR];   // R_lo^T image, padded
  __shared__ float    xLacc;

  const int ci   = blockIdx.x;
  const int b    = ci >> 5;
  const int cc   = ci & 31;
  const int tid  = threadIdx.x;
  const int wave = tid >> 6;
  const int lane = tid & 63;
  const int c    = lane & 15;
  const int h    = lane >> 4;
  const float* __restrict__ eb = emits + (size_t)b * (S_LEN * LL);

  // sequence length (mask is a contiguous prefix) — both waves compute
  int len;
  {
    const int* mb = mask + b * S_LEN;
    int cnt = 0;
    #pragma unroll
    for (int i = 0; i < 8; ++i) cnt += (mb[i * 64 + lane] != 0);
    #pragma unroll
    for (int off = 32; off; off >>= 1) cnt += __shfl_xor(cnt, off);
    len = cnt;
  }

  // gold partial (wave 0): emissions s in [16cc, 16cc+16) ∩ [0,len)
  if (wave == 0) {
    float g = 0.f;
    const int s = 16 * cc + (lane & 15);
    if (lane < 16 && s < len) {
      const int* tb = targets + b * (S_LEN + 1);
      g = eb[(size_t)s * LL + tb[s] * NL + tb[s + 1]];
    }
    #pragma unroll
    for (int off = 32; off; off >>= 1) g += __shfl_xor(g, off);
    if (lane == 0) wsf[NCHUNKS + ci] = g;
  }

  const int s0 = 16 * cc + 1;
  const int n  = min(len - s0, CL);
  if (n < 1) return;                      // uniform across block

  // wave 0: R_lo over s0..s0+n0-1 ; wave 1: R_hi over s0+8..s0+n-1
  const int n0    = min(n, 8);
  const int nw    = wave ? (n - n0) : n0;
  const int sbase = wave ? (s0 + 8) : s0;

  // R = Identity in B-frag layout: bf tile(K,J)[i] = (K==J && 4h+i==c)
  h4 bf[4][4];
  #pragma unroll
  for (int K = 0; K < 4; ++K)
    #pragma unroll
    for (int J = 0; J < 4; ++J) {
      h4 v;
      #pragma unroll
      for (int i = 0; i < 4; ++i)
        v[i] = (_Float16)((K == J && (4 * h + i) == c) ? 1.0f : 0.0f);
      bf[K][J] = v;
    }

  float Lacc = 0.f;
  f4 LB0[4][4], LB1[4][4];
  h4 af[4][4];

#define LOADE(LB, S)                                                         \
  do { const float* ep = eb + (size_t)(S) * LL;                              \
    _Pragma("unroll") for (int I = 0; I < 4; ++I) {                          \
      const float* rp = ep + (16 * I + c) * 64 + 4 * h;                      \
      _Pragma("unroll") for (int K = 0; K < 4; ++K)                          \
        LB[I][K] = *reinterpret_cast<const f4*>(rp + 16 * K);                \
    } } while (0)

#define BUILDAF(LB)                                                          \
  do { _Pragma("unroll") for (int I = 0; I < 4; ++I)                         \
    _Pragma("unroll") for (int K = 0; K < 4; ++K) {                          \
      U4 x;                                                                  \
      x.u[0] = pk2(expw(LB[I][K][0]), expw(LB[I][K][1]));                    \
      x.u[1] = pk2(expw(LB[I][K][2]), expw(LB[I][K][3]));                    \
      af[I][K] = x.v;                                                        \
    } } while (0)

  // one product step: D = M^T_s x R, lane-local rebuild, renorm at tail
#define STEPM(LBC, M)                                                        \
  do { if ((M) <= nw) {                                                      \
    BUILDAF(LBC);                                                            \
    if ((M) + 2 <= nw) LOADE(LBC, sbase + nw - 2 - (M));                     \
    const bool rn = ((M) == nw) || (((M) & 7) == 0);                         \
    float mh = 0.f;                                                          \
    { f4 dh[4][2];                                                           \
      _Pragma("unroll") for (int I = 0; I < 4; ++I)                          \
        _Pragma("unroll") for (int J = 0; J < 2; ++J) {                      \
          f4 d = {0.f, 0.f, 0.f, 0.f};                                       \
          _Pragma("unroll") for (int K = 0; K < 4; ++K)                      \
            d = __builtin_amdgcn_mfma_f32_16x16x16f16(af[I][K], bf[K][J], d, 0, 0, 0); \
          dh[I][J] = d;                                                      \
        }                                                                    \
      if (rn) { _Pragma("unroll") for (int I = 0; I < 4; ++I)                \
        _Pragma("unroll") for (int J = 0; J < 2; ++J)                        \
          _Pragma("unroll") for (int u = 0; u < 4; ++u)                      \
            mh = fmaxf(mh, dh[I][J][u]); }                                   \
      _Pragma("unroll") for (int K = 0; K < 4; ++K)                          \
        _Pragma("unroll") for (int J = 0; J < 2; ++J) {                      \
          U4 y;                                                              \
          y.u[0] = pk2(dh[K][J][0], dh[K][J][1]);                            \
          y.u[1] = pk2(dh[K][J][2], dh[K][J][3]);                            \
          bf[K][J] = y.v;                                                    \
        } }                                                                  \
    { f4 dh[4][2];                                                           \
      _Pragma("unroll") for (int I = 0; I < 4; ++I)                          \
        _Pragma("unroll") for (int J = 0; J < 2; ++J) {                      \
          f4 d = {0.f, 0.f, 0.f, 0.f};                                       \
          _Pragma("unroll") for (int K = 0; K < 4; ++K)                      \
            d = __builtin_amdgcn_mfma_f32_16x16x16f16(af[I][K], bf[K][J + 2], d, 0, 0, 0); \
          dh[I][J] = d;                                                      \
        }                                                                    \
      if (rn) { _Pragma("unroll") for (int I = 0; I < 4; ++I)                \
        _Pragma("unroll") for (int J = 0; J < 2; ++J)                        \
          _Pragma("unroll") for (int u = 0; u < 4; ++u)                      \
            mh = fmaxf(mh, dh[I][J][u]); }                                   \
      _Pragma("unroll") for (int K = 0; K < 4; ++K)                          \
        _Pragma("unroll") for (int J = 0; J < 2; ++J) {                      \
          U4 y;                                                              \
          y.u[0] = pk2(dh[K][J][0], dh[K][J][1]);                            \
          y.u[1] = pk2(dh[K][J][2], dh[K][J][3]);                            \
          bf[K][J + 2] = y.v;                                                \
        } }                                                                  \
    Lacc += PREF;                                                            \
    if (rn) {                                                                \
      _Pragma("unroll") for (int off = 32; off; off >>= 1)                   \
        mh = fmaxf(mh, __shfl_xor(mh, off));                                 \
      const int E = (__float_as_int(mh) >> 23) & 0xFF;                       \
      const _Float16 hs = (_Float16)__int_as_float((254 - E) << 23);         \
      const h4 hv = {hs, hs, hs, hs};                                        \
      _Pragma("unroll") for (int K = 0; K < 4; ++K)                          \
        _Pragma("unroll") for (int J = 0; J < 4; ++J) bf[K][J] *= hv;        \
      Lacc += (float)(E - 127) * LN2F;                                       \
    }                                                                        \
  } } while (0)

  if (nw >= 1) {
    LOADE(LB0, sbase + nw - 1);
    if (nw > 1) LOADE(LB1, sbase + nw - 2);
    for (int m = 1; m <= nw; m += 2) {
      STEPM(LB0, m);
      STEPM(LB1, m + 1);
    }
  }

  // ---- exchange: wave0 stores R_lo^T image; wave1 combines ----
  if (wave == 0) {
    #pragma unroll
    for (int K = 0; K < 4; ++K)
      #pragma unroll
      for (int J = 0; J < 4; ++J)
        *reinterpret_cast<h4*>(&xch[(16 * J + c) * XSTR + 16 * K + 4 * h]) = bf[K][J];
    if (lane == 0) xLacc = Lacc;
  }
  __syncthreads();

  if (wave == 1) {
    h4 afl[4][4];
    #pragma unroll
    for (int I = 0; I < 4; ++I)
      #pragma unroll
      for (int K = 0; K < 4; ++K)
        afl[I][K] = *reinterpret_cast<const h4*>(
            &xch[(16 * I + c) * XSTR + 16 * K + 4 * h]);

    // R = R_lo x R_hi = (R_lo^T)^T x R_hi
    float mh = 0.f;
    #pragma unroll
    for (int half = 0; half < 2; ++half) {
      f4 dh[4][2];
      #pragma unroll
      for (int I = 0; I < 4; ++I)
        #pragma unroll
        for (int J = 0; J < 2; ++J) {
          f4 d = {0.f, 0.f, 0.f, 0.f};
          #pragma unroll
          for (int K = 0; K < 4; ++K)
            d = __builtin_amdgcn_mfma_f32_16x16x16f16(
                afl[I][K], bf[K][J + 2 * half], d, 0, 0, 0);
          dh[I][J] = d;
        }
      #pragma unroll
      for (int I = 0; I < 4; ++I)
        #pragma unroll
        for (int J = 0; J < 2; ++J)
          #pragma unroll
          for (int u = 0; u < 4; ++u) mh = fmaxf(mh, dh[I][J][u]);
      #pragma unroll
      for (int K = 0; K < 4; ++K)
        #pragma unroll
        for (int J = 0; J < 2; ++J) {
          U4 y;
          y.u[0] = pk2(dh[K][J][0], dh[K][J][1]);
          y.u[1] = pk2(dh[K][J][2], dh[K][J][3]);
          bf[K][J + 2 * half] = y.v;
        }
    }
    #pragma unroll
    for (int off = 32; off; off >>= 1) mh = fmaxf(mh, __shfl_xor(mh, off));
    const int E = (__float_as_int(mh) >> 23) & 0xFF;
    const _Float16 hs = (_Float16)__int_as_float((254 - E) << 23);
    const h4 hv = {hs, hs, hs, hs};
    #pragma unroll
    for (int K = 0; K < 4; ++K)
      #pragma unroll
      for (int J = 0; J < 4; ++J) bf[K][J] *= hv;
    const float Ltot = Lacc + xLacc + (float)(E - 127) * LN2F;

    _Float16* mp = matP + (size_t)ci * 4096;
    #pragma unroll
    for (int I = 0; I < 4; ++I)
      #pragma unroll
      for (int J = 0; J < 4; ++J)
        #pragma unroll
        for (int i = 0; i < 4; ++i)
          mp[(I * 4 + J) * 256 + i * 64 + lane] = bf[I][J][i];
    if (lane == 0) wsf[ci] = Ltot;
  }
}

// ---------------- Phase 2: fold chunks into alpha0 (+ fused finale) --------
__global__ __launch_bounds__(64) void crf_fold(
    const float* __restrict__ emits,
    const int*   __restrict__ mask,
    const _Float16* __restrict__ matP,
    const float* __restrict__ wsf,
    float*       __restrict__ wso,   // [0,32): logz ; [32,64): len
    int*         __restrict__ done,
    float*       __restrict__ out)
{
  const int b = blockIdx.x, lane = threadIdx.x;
  const int c = lane & 15, h = lane >> 4;
  const float* __restrict__ eb = emits + (size_t)b * (S_LEN * LL);

  int len;
  {
    const int* mb = mask + b * S_LEN;
    int cnt = 0;
    #pragma unroll
    for (int i = 0; i < 8; ++i) cnt += (mb[i * 64 + lane] != 0);
    #pragma unroll
    for (int off = 32; off; off >>= 1) cnt += __shfl_xor(cnt, off);
    len = cnt;
  }
  const int nact = (len + 14) >> 4;   // chunks with >=1 matrix (len>=2)

  const bool on = (c == 0);
  const h4 HZ = {(_Float16)0, (_Float16)0, (_Float16)0, (_Float16)0};

  // alpha0[k] = E_0[BOS=0][k]
  float la[16];
  #pragma unroll
  for (int K = 0; K < 4; ++K)
    #pragma unroll
    for (int i = 0; i < 4; ++i) la[K * 4 + i] = eb[16 * K + 4 * h + i];
  float mm = la[0];
  #pragma unroll
  for (int i = 1; i < 16; ++i) mm = fmaxf(mm, la[i]);
  const float m0 = fmaxf(fmaxf(bl(mm, 0), bl(mm, 16)), fmaxf(bl(mm, 32), bl(mm, 48)));
  float Lacc = m0;
  h4 bv[4];
  #pragma unroll
  for (int K = 0; K < 4; ++K) {
    U4 y;
    y.u[0] = pk2(__expf(la[4 * K] - m0), __expf(la[4 * K + 1] - m0));
    y.u[1] = pk2(__expf(la[4 * K + 2] - m0), __expf(la[4 * K + 3] - m0));
    bv[K] = on ? y.v : HZ;
  }

  h4 A0[4][4], A1[4][4], A2[4][4], A3[4][4];   // depth-4 prefetch ring

#define LOADA(AF, CH)                                                        \
  do { const _Float16* mp = matP + (size_t)(b * NCH + (CH)) * 4096;          \
    _Pragma("unroll") for (int I = 0; I < 4; ++I)                            \
      _Pragma("unroll") for (int K = 0; K < 4; ++K)                          \
        AF[I][K] = *reinterpret_cast<const h4*>(                             \
            mp + (I * 4 + K) * 256 + (c & 3) * 64 + 16 * (c >> 2) + 4 * h);  \
  } while (0)

#define FOLD(AF, CH)                                                         \
  do { f4 dv[4];                                                             \
    _Pragma("unroll") for (int I = 0; I < 4; ++I) {                          \
      f4 d = {0.f, 0.f, 0.f, 0.f};                                           \
      _Pragma("unroll") for (int K = 0; K < 4; ++K)                          \
        d = __builtin_amdgcn_mfma_f32_16x16x16f16(AF[I][K], bv[K], d, 0, 0, 0); \
      dv[I] = d;                                                             \
    }                                                                        \
    float mx = dv[0][0];                                                     \
    _Pragma("unroll") for (int I = 0; I < 4; ++I)                            \
      _Pragma("unroll") for (int u = 0; u < 4; ++u) mx = fmaxf(mx, dv[I][u]); \
    float gm;                                                                \
    if (((CH) & 3) == 3) {                                                   \
      gm = fmaxf(fmaxf(bl(mx, 0), bl(mx, 16)),                               \
                 fmaxf(bl(mx, 32), bl(mx, 48)));                             \
    } else {                                                                 \
      gm = bl(mx, 0);                                                        \
    }                                                                        \
    const int E = (__float_as_int(gm) >> 23) & 0xFF;                         \
    const float scale = __int_as_float((254 - E) << 23);                     \
    Lacc += (float)(E - 127) * LN2F + wsf[b * NCH + (CH)];                   \
    _Pragma("unroll") for (int I = 0; I < 4; ++I) {                          \
      U4 y;                                                                  \
      y.u[0] = pk2(dv[I][0] * scale, dv[I][1] * scale);                      \
      y.u[1] = pk2(dv[I][2] * scale, dv[I][3] * scale);                      \
      bv[I] = on ? y.v : HZ;                                                 \
    } } while (0)

#define FSTEP(AF, APre, CH)                                                  \
  do { if ((CH) < nact) {                                                    \
    if ((CH) + 3 < nact) LOADA(APre, (CH) + 3);                              \
    FOLD(AF, (CH));                                                          \
  } } while (0)

  LOADA(A0, 0);
  if (1 < nact) LOADA(A1, 1);
  if (2 < nact) LOADA(A2, 2);
  for (int ch = 0; ch < nact; ch += 4) {
    FSTEP(A0, A3, ch);
    FSTEP(A1, A0, ch + 1);
    FSTEP(A2, A1, ch + 2);
    FSTEP(A3, A2, ch + 3);
  }

  float qs = 0.f;
  #pragma unroll
  for (int K = 0; K < 4; ++K)
    #pragma unroll
    for (int i = 0; i < 4; ++i) qs += (float)bv[K][i];
  const float q0 = (bl(qs, 0) + bl(qs, 16)) + (bl(qs, 32) + bl(qs, 48));
  if (lane == 0) {
    wso[b]      = Lacc + __logf(q0);
    wso[32 + b] = (float)len;
  }

  // ---- fused finale: last block to finish reduces everything ----
  __threadfence();
  int isLast = 0;
  if (lane == 0) isLast = (atomicAdd(done, 1) == NB - 1);
  isLast = __shfl(isLast, 0);
  if (isLast) {
    __threadfence();
    const float* gold = wsf + NCHUNKS;
    float gs = 0.f;
    #pragma unroll
    for (int i = 0; i < NCHUNKS / 64; ++i) gs += gold[i * 64 + lane];
    float lz = (lane < NB) ? wso[lane] : 0.f;
    float ln = (lane < NB) ? wso[32 + lane] : 0.f;
    #pragma unroll
    for (int off = 32; off; off >>= 1) {
      gs += __shfl_xor(gs, off);
      lz += __shfl_xor(lz, off);
      ln += __shfl_xor(ln, off);
    }
    if (lane == 0) out[0] = (lz - gs) / ln;
  }
}

extern "C" void kernel_launch(void* const* d_in, const int* in_sizes, int n_in,
                              void* d_out, int out_size, void* d_ws, size_t ws_size,
                              hipStream_t stream) {
  const float* emits   = (const float*)d_in[0];
  const int*   targets = (const int*)d_in[1];
  const int*   mask    = (const int*)d_in[2];
  float* out = (float*)d_out;

  _Float16* matP = (_Float16*)d_ws;                                   // 8 MB
  float*    wsf  = (float*)((char*)d_ws + (size_t)NCHUNKS * 4096 * 2);
  float*    wso  = wsf + 2 * NCHUNKS;
  int*      done = (int*)(wso + 64);

  hipMemsetAsync(done, 0, sizeof(int), stream);
  hipLaunchKernelGGL(crf_chunk, dim3(NCHUNKS), dim3(128), 0, stream,
                     emits, targets, mask, matP, wsf);
  // PROBE: fold launched 3x (idempotent; finale fires only in #1).
  hipLaunchKernelGGL(crf_fold, dim3(NB), dim3(64), 0, stream,
                     emits, mask, matP, wsf, wso, done, out);
  hipLaunchKernelGGL(crf_fold, dim3(NB), dim3(64), 0, stream,
                     emits, mask, matP, wsf, wso, done, out);
  hipLaunchKernelGGL(crf_fold, dim3(NB), dim3(64), 0, stream,
                     emits, mask, matP, wsf, wso, done, out);
}

// Round 19
// 65.242 us; speedup vs baseline: 1.8333x; 1.8333x over previous
//
#include <hip/hip_runtime.h>
#include <math.h>

// CRF forward loss, B=32, S=512, L=64 — chunked-matrix-product formulation.
// Round 19: tree-fold. R18 probe: chunk=33us (memory ceiling), fold=22us
// (latency: ~3400cyc/step x 16 serial steps), overhead=20us. New fold:
// 4 waves/batch each build Q_w = product of 8 chunk matrices (matrix-matrix,
// 64 MFMA/step covers load latency), then wave0 applies 4 LDS-resident
// mat-vecs. Serial chain 32 -> 8+4. Memset node removed (chunk zeroes done).

constexpr int S_LEN   = 512;
constexpr int NB      = 32;
constexpr int NL      = 64;
constexpr int LL      = 4096;
constexpr int CL      = 16;
constexpr int NCH     = 32;            // chunks per batch
constexpr int NCHUNKS = NB * NCH;      // 1024
constexpr int XSTR    = 68;            // padded exchange stride (f16)

#define LN2F 0.69314718055994531f
#define PREF 4.6588830833596715f       /* ln(64)+0.5 : M = exp(E)*e^-PREF */

typedef _Float16 h4 __attribute__((ext_vector_type(4)));
typedef float    f4 __attribute__((ext_vector_type(4)));
union U4 { unsigned u[2]; h4 v; };

__device__ __forceinline__ float bl(float v, int sl) {
  return __int_as_float(__builtin_amdgcn_readlane(__float_as_int(v), sl));
}
__device__ __forceinline__ unsigned pk2(float a, float b) {
  auto r = __builtin_amdgcn_cvt_pkrtz(a, b);
  return __builtin_bit_cast(unsigned, r);
}
__device__ __forceinline__ float expw(float x) {   // exp(x)*e^-PREF, native
  return __expf(x - PREF);
}

// ---------------- Phase 1: chunk products (2-wave split chain) --------------
__global__ __launch_bounds__(128, 2) void crf_chunk(
    const float* __restrict__ emits,
    const int*   __restrict__ targets,
    const int*   __restrict__ mask,
    _Float16*    __restrict__ matP,   // [1024][4096] f16
    float*       __restrict__ wsf,    // [0,1024): Lacc ; [1024,2048): gold
    int*         __restrict__ done)
{
  __shared__ _Float16 xch[64 * XSTR];   // R_lo^T image, padded
  __shared__ float    xLacc;

  const int ci   = blockIdx.x;
  const int b    = ci >> 5;
  const int cc   = ci & 31;
  const int tid  = threadIdx.x;
  const int wave = tid >> 6;
  const int lane = tid & 63;
  const int c    = lane & 15;
  const int h    = lane >> 4;
  const float* __restrict__ eb = emits + (size_t)b * (S_LEN * LL);

  if (ci == 0 && tid == 0) *done = 0;   // replaces the memset node

  // sequence length (mask is a contiguous prefix) — both waves compute
  int len;
  {
    const int* mb = mask + b * S_LEN;
    int cnt = 0;
    #pragma unroll
    for (int i = 0; i < 8; ++i) cnt += (mb[i * 64 + lane] != 0);
    #pragma unroll
    for (int off = 32; off; off >>= 1) cnt += __shfl_xor(cnt, off);
    len = cnt;
  }

  // gold partial (wave 0): emissions s in [16cc, 16cc+16) ∩ [0,len)
  if (wave == 0) {
    float g = 0.f;
    const int s = 16 * cc + (lane & 15);
    if (lane < 16 && s < len) {
      const int* tb = targets + b * (S_LEN + 1);
      g = eb[(size_t)s * LL + tb[s] * NL + tb[s + 1]];
    }
    #pragma unroll
    for (int off = 32; off; off >>= 1) g += __shfl_xor(g, off);
    if (lane == 0) wsf[NCHUNKS + ci] = g;
  }

  const int s0 = 16 * cc + 1;
  const int n  = min(len - s0, CL);
  if (n < 1) return;                      // uniform across block

  const int n0    = min(n, 8);
  const int nw    = wave ? (n - n0) : n0;
  const int sbase = wave ? (s0 + 8) : s0;

  // R = Identity in B-frag layout
  h4 bf[4][4];
  #pragma unroll
  for (int K = 0; K < 4; ++K)
    #pragma unroll
    for (int J = 0; J < 4; ++J) {
      h4 v;
      #pragma unroll
      for (int i = 0; i < 4; ++i)
        v[i] = (_Float16)((K == J && (4 * h + i) == c) ? 1.0f : 0.0f);
      bf[K][J] = v;
    }

  float Lacc = 0.f;
  f4 LB0[4][4], LB1[4][4];
  h4 af[4][4];

#define LOADE(LB, S)                                                         \
  do { const float* ep = eb + (size_t)(S) * LL;                              \
    _Pragma("unroll") for (int I = 0; I < 4; ++I) {                          \
      const float* rp = ep + (16 * I + c) * 64 + 4 * h;                      \
      _Pragma("unroll") for (int K = 0; K < 4; ++K)                          \
        LB[I][K] = *reinterpret_cast<const f4*>(rp + 16 * K);                \
    } } while (0)

#define BUILDAF(LB)                                                          \
  do { _Pragma("unroll") for (int I = 0; I < 4; ++I)                         \
    _Pragma("unroll") for (int K = 0; K < 4; ++K) {                          \
      U4 x;                                                                  \
      x.u[0] = pk2(expw(LB[I][K][0]), expw(LB[I][K][1]));                    \
      x.u[1] = pk2(expw(LB[I][K][2]), expw(LB[I][K][3]));                    \
      af[I][K] = x.v;                                                        \
    } } while (0)

#define STEPM(LBC, M)                                                        \
  do { if ((M) <= nw) {                                                      \
    BUILDAF(LBC);                                                            \
    if ((M) + 2 <= nw) LOADE(LBC, sbase + nw - 2 - (M));                     \
    const bool rn = ((M) == nw) || (((M) & 7) == 0);                         \
    float mh = 0.f;                                                          \
    { f4 dh[4][2];                                                           \
      _Pragma("unroll") for (int I = 0; I < 4; ++I)                          \
        _Pragma("unroll") for (int J = 0; J < 2; ++J) {                      \
          f4 d = {0.f, 0.f, 0.f, 0.f};                                       \
          _Pragma("unroll") for (int K = 0; K < 4; ++K)                      \
            d = __builtin_amdgcn_mfma_f32_16x16x16f16(af[I][K], bf[K][J], d, 0, 0, 0); \
          dh[I][J] = d;                                                      \
        }                                                                    \
      if (rn) { _Pragma("unroll") for (int I = 0; I < 4; ++I)                \
        _Pragma("unroll") for (int J = 0; J < 2; ++J)                        \
          _Pragma("unroll") for (int u = 0; u < 4; ++u)                      \
            mh = fmaxf(mh, dh[I][J][u]); }                                   \
      _Pragma("unroll") for (int K = 0; K < 4; ++K)                          \
        _Pragma("unroll") for (int J = 0; J < 2; ++J) {                      \
          U4 y;                                                              \
          y.u[0] = pk2(dh[K][J][0], dh[K][J][1]);                            \
          y.u[1] = pk2(dh[K][J][2], dh[K][J][3]);                            \
          bf[K][J] = y.v;                                                    \
        } }                                                                  \
    { f4 dh[4][2];                                                           \
      _Pragma("unroll") for (int I = 0; I < 4; ++I)                          \
        _Pragma("unroll") for (int J = 0; J < 2; ++J) {                      \
          f4 d = {0.f, 0.f, 0.f, 0.f};                                       \
          _Pragma("unroll") for (int K = 0; K < 4; ++K)                      \
            d = __builtin_amdgcn_mfma_f32_16x16x16f16(af[I][K], bf[K][J + 2], d, 0, 0, 0); \
          dh[I][J] = d;                                                      \
        }                                                                    \
      if (rn) { _Pragma("unroll") for (int I = 0; I < 4; ++I)                \
        _Pragma("unroll") for (int J = 0; J < 2; ++J)                        \
          _Pragma("unroll") for (int u = 0; u < 4; ++u)                      \
            mh = fmaxf(mh, dh[I][J][u]); }                                   \
      _Pragma("unroll") for (int K = 0; K < 4; ++K)                          \
        _Pragma("unroll") for (int J = 0; J < 2; ++J) {                      \
          U4 y;                                                              \
          y.u[0] = pk2(dh[K][J][0], dh[K][J][1]);                            \
          y.u[1] = pk2(dh[K][J][2], dh[K][J][3]);                            \
          bf[K][J + 2] = y.v;                                                \
        } }                                                                  \
    Lacc += PREF;                                                            \
    if (rn) {                                                                \
      _Pragma("unroll") for (int off = 32; off; off >>= 1)                   \
        mh = fmaxf(mh, __shfl_xor(mh, off));                                 \
      const int E = (__float_as_int(mh) >> 23) & 0xFF;                       \
      const _Float16 hs = (_Float16)__int_as_float((254 - E) << 23);         \
      const h4 hv = {hs, hs, hs, hs};                                        \
      _Pragma("unroll") for (int K = 0; K < 4; ++K)                          \
        _Pragma("unroll") for (int J = 0; J < 4; ++J) bf[K][J] *= hv;        \
      Lacc += (float)(E - 127) * LN2F;                                       \
    }                                                                        \
  } } while (0)

  if (nw >= 1) {
    LOADE(LB0, sbase + nw - 1);
    if (nw > 1) LOADE(LB1, sbase + nw - 2);
    for (int m = 1; m <= nw; m += 2) {
      STEPM(LB0, m);
      STEPM(LB1, m + 1);
    }
  }

  // ---- exchange: wave0 stores R_lo^T image; wave1 combines ----
  if (wave == 0) {
    #pragma unroll
    for (int K = 0; K < 4; ++K)
      #pragma unroll
      for (int J = 0; J < 4; ++J)
        *reinterpret_cast<h4*>(&xch[(16 * J + c) * XSTR + 16 * K + 4 * h]) = bf[K][J];
    if (lane == 0) xLacc = Lacc;
  }
  __syncthreads();

  if (wave == 1) {
    h4 afl[4][4];
    #pragma unroll
    for (int I = 0; I < 4; ++I)
      #pragma unroll
      for (int K = 0; K < 4; ++K)
        afl[I][K] = *reinterpret_cast<const h4*>(
            &xch[(16 * I + c) * XSTR + 16 * K + 4 * h]);

    float mh = 0.f;
    #pragma unroll
    for (int half = 0; half < 2; ++half) {
      f4 dh[4][2];
      #pragma unroll
      for (int I = 0; I < 4; ++I)
        #pragma unroll
        for (int J = 0; J < 2; ++J) {
          f4 d = {0.f, 0.f, 0.f, 0.f};
          #pragma unroll
          for (int K = 0; K < 4; ++K)
            d = __builtin_amdgcn_mfma_f32_16x16x16f16(
                afl[I][K], bf[K][J + 2 * half], d, 0, 0, 0);
          dh[I][J] = d;
        }
      #pragma unroll
      for (int I = 0; I < 4; ++I)
        #pragma unroll
        for (int J = 0; J < 2; ++J)
          #pragma unroll
          for (int u = 0; u < 4; ++u) mh = fmaxf(mh, dh[I][J][u]);
      #pragma unroll
      for (int K = 0; K < 4; ++K)
        #pragma unroll
        for (int J = 0; J < 2; ++J) {
          U4 y;
          y.u[0] = pk2(dh[K][J][0], dh[K][J][1]);
          y.u[1] = pk2(dh[K][J][2], dh[K][J][3]);
          bf[K][J + 2 * half] = y.v;
        }
    }
    #pragma unroll
    for (int off = 32; off; off >>= 1) mh = fmaxf(mh, __shfl_xor(mh, off));
    const int E = (__float_as_int(mh) >> 23) & 0xFF;
    const _Float16 hs = (_Float16)__int_as_float((254 - E) << 23);
    const h4 hv = {hs, hs, hs, hs};
    #pragma unroll
    for (int K = 0; K < 4; ++K)
      #pragma unroll
      for (int J = 0; J < 4; ++J) bf[K][J] *= hv;
    const float Ltot = Lacc + xLacc + (float)(E - 127) * LN2F;

    _Float16* mp = matP + (size_t)ci * 4096;
    #pragma unroll
    for (int I = 0; I < 4; ++I)
      #pragma unroll
      for (int J = 0; J < 4; ++J)
        #pragma unroll
        for (int i = 0; i < 4; ++i)
          mp[(I * 4 + J) * 256 + i * 64 + lane] = bf[I][J][i];
    if (lane == 0) wsf[ci] = Ltot;
  }
}

// ---------------- Phase 2: tree-fold (4 waves/batch) ------------------------
__global__ __launch_bounds__(256) void crf_fold(
    const float* __restrict__ emits,
    const int*   __restrict__ mask,
    const _Float16* __restrict__ matP,
    const float* __restrict__ wsf,
    float*       __restrict__ wso,   // [0,32): logz ; [32,64): len
    int*         __restrict__ done,
    float*       __restrict__ out)
{
  __shared__ _Float16 xq[4][64 * XSTR];   // Q_w images
  __shared__ float    xL[4];

  const int b    = blockIdx.x;
  const int tid  = threadIdx.x;
  const int wave = tid >> 6;
  const int lane = tid & 63;
  const int c    = lane & 15;
  const int h    = lane >> 4;
  const float* __restrict__ eb = emits + (size_t)b * (S_LEN * LL);

  int len;
  {
    const int* mb = mask + b * S_LEN;
    int cnt = 0;
    #pragma unroll
    for (int i = 0; i < 8; ++i) cnt += (mb[i * 64 + lane] != 0);
    #pragma unroll
    for (int off = 32; off; off >>= 1) cnt += __shfl_xor(cnt, off);
    len = cnt;
  }
  const int nact = (len + 14) >> 4;   // chunks with >=1 matrix

  // ---- every wave: matrix chain Q_w over chunks [8w, min(nact,8w+8)) ----
  const int j0 = 8 * wave;
  const int j1 = min(nact, j0 + 8);

  h4 bf[4][4];   // Q accumulator, identity init
  #pragma unroll
  for (int K = 0; K < 4; ++K)
    #pragma unroll
    for (int J = 0; J < 4; ++J) {
      h4 v;
      #pragma unroll
      for (int i = 0; i < 4; ++i)
        v[i] = (_Float16)((K == J && (4 * h + i) == c) ? 1.0f : 0.0f);
      bf[K][J] = v;
    }
  float LaccQ = 0.f;

  h4 A0[4][4], A1[4][4], A2[4][4];   // 3-buffer ring, depth-2 prefetch

#define LOADA(AF, CH)                                                        \
  do { const _Float16* mp = matP + (size_t)(b * NCH + (CH)) * 4096;          \
    _Pragma("unroll") for (int I = 0; I < 4; ++I)                            \
      _Pragma("unroll") for (int K = 0; K < 4; ++K)                          \
        AF[I][K] = *reinterpret_cast<const h4*>(                             \
            mp + (I * 4 + K) * 256 + (c & 3) * 64 + 16 * (c >> 2) + 4 * h);  \
  } while (0)

  // matrix product step: bf := P^T_jj x bf  (J-halved)
#define MPROD(ACUR, RNFULL, JJ)                                              \
  do {                                                                       \
    float mh = 0.f;                                                          \
    { f4 dh[4][2];                                                           \
      _Pragma("unroll") for (int I = 0; I < 4; ++I)                          \
        _Pragma("unroll") for (int J = 0; J < 2; ++J) {                      \
          f4 d = {0.f, 0.f, 0.f, 0.f};                                       \
          _Pragma("unroll") for (int K = 0; K < 4; ++K)                      \
            d = __builtin_amdgcn_mfma_f32_16x16x16f16(ACUR[I][K], bf[K][J], d, 0, 0, 0); \
          dh[I][J] = d;                                                      \
        }                                                                    \
      _Pragma("unroll") for (int I = 0; I < 4; ++I)                          \
        _Pragma("unroll") for (int J = 0; J < 2; ++J)                        \
          _Pragma("unroll") for (int u = 0; u < 4; ++u)                      \
            mh = fmaxf(mh, dh[I][J][u]);                                     \
      _Pragma("unroll") for (int K = 0; K < 4; ++K)                          \
        _Pragma("unroll") for (int J = 0; J < 2; ++J) {                      \
          U4 y;                                                              \
          y.u[0] = pk2(dh[K][J][0], dh[K][J][1]);                            \
          y.u[1] = pk2(dh[K][J][2], dh[K][J][3]);                            \
          bf[K][J] = y.v;                                                    \
        } }                                                                  \
    { f4 dh[4][2];                                                           \
      _Pragma("unroll") for (int I = 0; I < 4; ++I)                          \
        _Pragma("unroll") for (int J = 0; J < 2; ++J) {                      \
          f4 d = {0.f, 0.f, 0.f, 0.f};                                       \
          _Pragma("unroll") for (int K = 0; K < 4; ++K)                      \
            d = __builtin_amdgcn_mfma_f32_16x16x16f16(ACUR[I][K], bf[K][J + 2], d, 0, 0, 0); \
          dh[I][J] = d;                                                      \
        }                                                                    \
      _Pragma("unroll") for (int I = 0; I < 4; ++I)                          \
        _Pragma("unroll") for (int J = 0; J < 2; ++J)                        \
          _Pragma("unroll") for (int u = 0; u < 4; ++u)                      \
            mh = fmaxf(mh, dh[I][J][u]);                                     \
      _Pragma("unroll") for (int K = 0; K < 4; ++K)                          \
        _Pragma("unroll") for (int J = 0; J < 2; ++J) {                      \
          U4 y;                                                              \
          y.u[0] = pk2(dh[K][J][0], dh[K][J][1]);                            \
          y.u[1] = pk2(dh[K][J][2], dh[K][J][3]);                            \
          bf[K][J + 2] = y.v;                                                \
        } }                                                                  \
    float gm;                                                                \
    if (RNFULL) {                                                            \
      _Pragma("unroll") for (int off = 32; off; off >>= 1)                   \
        mh = fmaxf(mh, __shfl_xor(mh, off));                                 \
      gm = mh;                                                               \
    } else {                                                                 \
      gm = bl(mh, 0);                                                        \
    }                                                                        \
    const int E = (__float_as_int(gm) >> 23) & 0xFF;                         \
    const _Float16 hs = (_Float16)__int_as_float((254 - E) << 23);           \
    const h4 hv = {hs, hs, hs, hs};                                          \
    _Pragma("unroll") for (int K = 0; K < 4; ++K)                            \
      _Pragma("unroll") for (int J = 0; J < 4; ++J) bf[K][J] *= hv;          \
    LaccQ += (float)(E - 127) * LN2F + wsf[b * NCH + (JJ)];                  \
  } while (0)

#define QSTEP(ACUR, APRE, KO)                                                \
  do { const int jj = j0 + (KO);                                             \
    if (jj < j1) {                                                           \
      if (jj + 2 < j1) LOADA(APRE, jj + 2);                                  \
      MPROD(ACUR, ((((KO) & 1) == 1) || (jj == j1 - 1)), jj);                \
    } } while (0)

  if (j0 < j1) {
    LOADA(A0, j0);
    if (j0 + 1 < j1) LOADA(A1, j0 + 1);
    QSTEP(A0, A2, 0);
    QSTEP(A1, A0, 1);
    QSTEP(A2, A1, 2);
    QSTEP(A0, A2, 3);
    QSTEP(A1, A0, 4);
    QSTEP(A2, A1, 5);
    QSTEP(A0, A2, 6);
    QSTEP(A1, A0, 7);
  }

  // store Q_w image (R17-validated layout) + LaccQ
  #pragma unroll
  for (int K = 0; K < 4; ++K)
    #pragma unroll
    for (int J = 0; J < 4; ++J)
      *reinterpret_cast<h4*>(&xq[wave][(16 * J + c) * XSTR + 16 * K + 4 * h]) = bf[K][J];
  if (lane == 0) xL[wave] = LaccQ;
  __syncthreads();

  if (wave != 0) return;

  // ---- wave 0: alpha0, then v := Q_3(Q_2(Q_1(Q_0 v))) ----
  const bool on = (c == 0);
  const h4 HZ = {(_Float16)0, (_Float16)0, (_Float16)0, (_Float16)0};

  float la[16];
  #pragma unroll
  for (int K = 0; K < 4; ++K)
    #pragma unroll
    for (int i = 0; i < 4; ++i) la[K * 4 + i] = eb[16 * K + 4 * h + i];
  float mm = la[0];
  #pragma unroll
  for (int i = 1; i < 16; ++i) mm = fmaxf(mm, la[i]);
  const float m0 = fmaxf(fmaxf(bl(mm, 0), bl(mm, 16)), fmaxf(bl(mm, 32), bl(mm, 48)));
  float Lacc = m0;
  h4 bv[4];
  #pragma unroll
  for (int K = 0; K < 4; ++K) {
    U4 y;
    y.u[0] = pk2(__expf(la[4 * K] - m0), __expf(la[4 * K + 1] - m0));
    y.u[1] = pk2(__expf(la[4 * K + 2] - m0), __expf(la[4 * K + 3] - m0));
    bv[K] = on ? y.v : HZ;
  }

#define APPLYQ(W, LASTF)                                                     \
  do {                                                                       \
    h4 afl[4][4];                                                            \
    _Pragma("unroll") for (int I = 0; I < 4; ++I)                            \
      _Pragma("unroll") for (int K = 0; K < 4; ++K)                          \
        afl[I][K] = *reinterpret_cast<const h4*>(                            \
            &xq[W][(16 * I + c) * XSTR + 16 * K + 4 * h]);                   \
    f4 dv[4];                                                                \
    _Pragma("unroll") for (int I = 0; I < 4; ++I) {                          \
      f4 d = {0.f, 0.f, 0.f, 0.f};                                           \
      _Pragma("unroll") for (int K = 0; K < 4; ++K)                          \
        d = __builtin_amdgcn_mfma_f32_16x16x16f16(afl[I][K], bv[K], d, 0, 0, 0); \
      dv[I] = d;                                                             \
    }                                                                        \
    float mx = dv[0][0];                                                     \
    _Pragma("unroll") for (int I = 0; I < 4; ++I)                            \
      _Pragma("unroll") for (int u = 0; u < 4; ++u) mx = fmaxf(mx, dv[I][u]); \
    float gm;                                                                \
    if (LASTF) {                                                             \
      _Pragma("unroll") for (int off = 32; off; off >>= 1)                   \
        mx = fmaxf(mx, __shfl_xor(mx, off));                                 \
      gm = mx;                                                               \
    } else {                                                                 \
      gm = bl(mx, 0);                                                        \
    }                                                                        \
    const int E = (__float_as_int(gm) >> 23) & 0xFF;                         \
    const float scale = __int_as_float((254 - E) << 23);                     \
    Lacc += (float)(E - 127) * LN2F + xL[W];                                 \
    _Pragma("unroll") for (int I = 0; I < 4; ++I) {                          \
      U4 y;                                                                  \
      y.u[0] = pk2(dv[I][0] * scale, dv[I][1] * scale);                      \
      y.u[1] = pk2(dv[I][2] * scale, dv[I][3] * scale);                      \
      bv[I] = on ? y.v : HZ;                                                 \
    } } while (0)

  APPLYQ(0, false);
  APPLYQ(1, false);
  APPLYQ(2, false);
  APPLYQ(3, true);

  float qs = 0.f;
  #pragma unroll
  for (int K = 0; K < 4; ++K)
    #pragma unroll
    for (int i = 0; i < 4; ++i) qs += (float)bv[K][i];
  const float q0 = (bl(qs, 0) + bl(qs, 16)) + (bl(qs, 32) + bl(qs, 48));
  if (lane == 0) {
    wso[b]      = Lacc + __logf(q0);
    wso[32 + b] = (float)len;
  }

  // ---- fused finale: last block to finish reduces everything ----
  __threadfence();
  int isLast = 0;
  if (lane == 0) isLast = (atomicAdd(done, 1) == NB - 1);
  isLast = __shfl(isLast, 0);
  if (isLast) {
    __threadfence();
    const float* gold = wsf + NCHUNKS;
    float gs = 0.f;
    #pragma unroll
    for (int i = 0; i < NCHUNKS / 64; ++i) gs += gold[i * 64 + lane];
    float lz = (lane < NB) ? wso[lane] : 0.f;
    float ln = (lane < NB) ? wso[32 + lane] : 0.f;
    #pragma unroll
    for (int off = 32; off; off >>= 1) {
      gs += __shfl_xor(gs, off);
      lz += __shfl_xor(lz, off);
      ln += __shfl_xor(ln, off);
    }
    if (lane == 0) out[0] = (lz - gs) / ln;
  }
}

extern "C" void kernel_launch(void* const* d_in, const int* in_sizes, int n_in,
                              void* d_out, int out_size, void* d_ws, size_t ws_size,
                              hipStream_t stream) {
  const float* emits   = (const float*)d_in[0];
  const int*   targets = (const int*)d_in[1];
  const int*   mask    = (const int*)d_in[2];
  float* out = (float*)d_out;

  _Float16* matP = (_Float16*)d_ws;                                   // 8 MB
  float*    wsf  = (float*)((char*)d_ws + (size_t)NCHUNKS * 4096 * 2);
  float*    wso  = wsf + 2 * NCHUNKS;
  int*      done = (int*)(wso + 64);

  hipLaunchKernelGGL(crf_chunk, dim3(NCHUNKS), dim3(128), 0, stream,
                     emits, targets, mask, matP, wsf, done);
  hipLaunchKernelGGL(crf_fold, dim3(NB), dim3(256), 0, stream,
                     emits, mask, matP, wsf, wso, done, out);
}